// Round 13
// baseline (194.204 us; speedup 1.0000x reference)
//
#include <hip/hip_runtime.h>
#include <math.h>

#define F_OUT     32
#define GRID_DIM  32
#define NUM_VOX   (GRID_DIM * GRID_DIM * GRID_DIM)

#define NPB   64             // nodes per bucket; bucket = dst >> 6
#define NBKT  1024           // bucket table size (Nn <= 65536)
#define SEB   4096           // edges per sort block
#define SCS   132            // sC row stride (floats): 528 B, 16B-aligned
#define DEGS  125            // degree slot within sC row
#define OWN_BLOCKS 512       // persistent owner blocks (2 buckets each)

// ---------- monotonic float<->uint encoding for atomicMax on signed floats ----
__device__ __forceinline__ unsigned int enc_f32(float f) {
    unsigned int u = __float_as_uint(f);
    return (u & 0x80000000u) ? ~u : (u | 0x80000000u);
}
__device__ __forceinline__ float dec_f32(unsigned int e) {
    return (e & 0x80000000u) ? __uint_as_float(e ^ 0x80000000u)
                             : __uint_as_float(~e);
}

// ---------- K1: block-local counting sort (R11 form), MLP-8 pass A -----------
__global__ __launch_bounds__(512) void sort_kernel(
    const int*   __restrict__ src,
    const int*   __restrict__ dst,
    const float* __restrict__ x,
    const float* __restrict__ pseudo,
    float4* __restrict__ payload,          // [nSB * SEB]
    unsigned int* __restrict__ off_tab,    // [nSB][NBKT] packed: local_start | cnt<<16
    int E)
{
    __shared__ unsigned int sHist[NBKT];
    __shared__ unsigned int sStart[NBKT];
    __shared__ unsigned int sWTot[8];
    __shared__ __align__(16) float4 sPay[SEB];   // 64 KB

    const int t    = threadIdx.x;
    const int lane = t & 63;
    const int wv   = t >> 6;
    const int e0   = blockIdx.x * SEB;
    const bool full = (e0 + SEB <= E);

    for (int i = t; i < NBKT; i += 512) sHist[i] = 0;
    __syncthreads();

    // pass A: batched loads -> 8 independent x-gathers in flight -> histogram.
    // validity = index range (e < E); dst==65535 is a legal id, no sentinel.
    unsigned short dloc[8];
    float4 pay[8];
    if (full) {
        int   dd[8], ss[8];
        float pp0[8], pp1[8], pp2[8], xj[8];
        #pragma unroll
        for (int i = 0; i < 8; ++i) {
            int e = e0 + i * 512 + t;
            dd[i] = dst[e]; ss[i] = src[e];
            pp0[i] = pseudo[3 * e]; pp1[i] = pseudo[3 * e + 1]; pp2[i] = pseudo[3 * e + 2];
        }
        #pragma unroll
        for (int i = 0; i < 8; ++i) xj[i] = x[ss[i]];
        #pragma unroll
        for (int i = 0; i < 8; ++i) {
            unsigned int q2 = (unsigned int)(pp2[i] * 65535.0f + 0.5f) & 0xFFFFu;
            unsigned int w  = q2 | ((unsigned int)(dd[i] & 63) << 16);
            dloc[i] = (unsigned short)dd[i];
            pay[i]  = make_float4(pp0[i], pp1[i], xj[i], __uint_as_float(w));
            atomicAdd(&sHist[dd[i] >> 6], 1u);
        }
    } else {
        #pragma unroll
        for (int i = 0; i < 8; ++i) {
            int e = e0 + i * 512 + t;
            if (e < E) {
                int d = dst[e];
                float p0 = pseudo[3 * e], p1 = pseudo[3 * e + 1], p2 = pseudo[3 * e + 2];
                float xjv = x[src[e]];
                unsigned int q2 = (unsigned int)(p2 * 65535.0f + 0.5f) & 0xFFFFu;
                unsigned int w  = q2 | ((unsigned int)(d & 63) << 16);
                dloc[i] = (unsigned short)d;
                pay[i]  = make_float4(p0, p1, xjv, __uint_as_float(w));
                atomicAdd(&sHist[d >> 6], 1u);
            } else dloc[i] = 0;
        }
    }
    __syncthreads();

    // exclusive scan of 1024 buckets: pair-sum + wave shfl-scan + cross-wave
    unsigned int a0 = sHist[2 * t], a1 = sHist[2 * t + 1];
    unsigned int pairSum = a0 + a1;
    unsigned int incl = pairSum;
    #pragma unroll
    for (int d = 1; d < 64; d <<= 1) {
        unsigned int v = __shfl_up(incl, d, 64);
        if (lane >= d) incl += v;
    }
    if (lane == 63) sWTot[wv] = incl;
    __syncthreads();
    unsigned int wofs = 0, total = 0;
    #pragma unroll
    for (int w = 0; w < 8; ++w) {
        unsigned int v = sWTot[w];
        if (w < wv) wofs += v;
        total += v;
    }
    unsigned int ex = wofs + incl - pairSum;
    sStart[2 * t]     = ex;
    sStart[2 * t + 1] = ex + a0;
    sHist[2 * t]      = ex;            // cursor copy
    sHist[2 * t + 1]  = ex + a0;
    __syncthreads();

    // pass B: place payloads into LDS by bucket
    #pragma unroll
    for (int i = 0; i < 8; ++i) {
        int e = e0 + i * 512 + t;
        if (e < E) {
            unsigned int slot = atomicAdd(&sHist[dloc[i] >> 6], 1u);
            sPay[slot] = pay[i];
        }
    }
    __syncthreads();

    // streamout: coalesced 16B stores
    for (unsigned int i = t; i < total; i += 512)
        payload[(size_t)e0 + i] = sPay[i];

    // packed offset table, coalesced row write
    for (int b = t; b < NBKT; b += 512) {
        unsigned int s = sStart[b];
        unsigned int nxt = (b < NBKT - 1) ? sStart[b + 1] : total;
        off_tab[(size_t)blockIdx.x * NBKT + b] = s | ((nxt - s) << 16);
    }
}

// ---------- K1b: transpose off_tab [nSB][NBKT] -> [NBKT][nSB] ----------------
__global__ __launch_bounds__(256) void transpose_kernel(
    const unsigned int* __restrict__ in, unsigned int* __restrict__ outT,
    int rows, int cols)
{
    __shared__ unsigned int tile[32][33];
    const int tx = threadIdx.x & 31, ty = threadIdx.x >> 5;   // 32x8
    const int c0 = blockIdx.x * 32, r0 = blockIdx.y * 32;
    #pragma unroll
    for (int r = ty; r < 32; r += 8) {
        int row = r0 + r, col = c0 + tx;
        tile[r][tx] = (row < rows && col < cols) ? in[(size_t)row * cols + col] : 0u;
    }
    __syncthreads();
    #pragma unroll
    for (int r = ty; r < 32; r += 8) {
        int col = c0 + r;
        int row = r0 + tx;
        if (col < cols && row < rows) outT[(size_t)col * rows + row] = tile[tx][r];
    }
}

// ---------- per-edge accumulation: 9 scattered LDS atomics -------------------
// w layout: q2(16) | rel(6)<<16
__device__ __forceinline__ void process_edge(float4 r, float* sC)
{
    float xj = r.z;
    unsigned int w = __float_as_uint(r.w);
    int   rel = (int)((w >> 16) & 63u);
    float p2  = (float)(w & 0xFFFFu) * (1.0f / 65535.0f);

    float v0 = r.x * 4.0f, v1 = r.y * 4.0f, v2 = p2 * 4.0f;
    float i0 = fminf(fmaxf(floorf(v0), 0.0f), 3.0f);
    float i1 = fminf(fmaxf(floorf(v1), 0.0f), 3.0f);
    float i2 = fminf(fmaxf(floorf(v2), 0.0f), 3.0f);
    float f0 = v0 - i0, f1 = v1 - i1, f2 = v2 - i2;
    float g0 = 1.0f - f0, g1 = 1.0f - f1, g2 = 1.0f - f2;
    int k = (int)i0 + 5 * (int)i1 + 25 * (int)i2;        // 0..93

    float w00 = g0 * g1, w10 = f0 * g1, w01 = g0 * f1, w11 = f0 * f1;
    float a2 = xj * g2, b2 = xj * f2;
    float* row = sC + rel * SCS;
    atomicAdd(row + k +  0, w00 * a2);
    atomicAdd(row + k +  1, w10 * a2);
    atomicAdd(row + k +  5, w01 * a2);
    atomicAdd(row + k +  6, w11 * a2);
    atomicAdd(row + k + 25, w00 * b2);
    atomicAdd(row + k + 26, w10 * b2);
    atomicAdd(row + k + 30, w01 * b2);
    atomicAdd(row + k + 31, w11 * b2);
    atomicAdd(row + DEGS, 1.0f);                         // degree
}

// ---------- K2: persistent owner — fragment-serial accumulate + GEMM + voxmax
__global__ __launch_bounds__(256) void owner_kernel(
    const float4* __restrict__ payload,
    const unsigned int* __restrict__ off_tabT,  // [NBKT][nSB] packed (transposed)
    const float* __restrict__ W,        // [125,32]
    const float* __restrict__ x,        // [N,1]
    const float* __restrict__ W_root,   // [32]
    const float* __restrict__ bias,     // [32]
    const float* __restrict__ pos,      // [N,3]
    unsigned int* __restrict__ pooled,  // [NUM_VOX,32] encoded
    int Nn, int nSB, int nb)
{
    __shared__ __align__(16) float sC[NPB * SCS];   // 33792 B (only LDS)

    const int t = threadIdx.x;

    for (int b = blockIdx.x; b < nb; b += gridDim.x) {
        // zero sC (re-used across grid-stride iterations)
        for (int i = t; i < NPB * SCS / 4; i += 256)
            *(float4*)&sC[i * 4] = make_float4(0.f, 0.f, 0.f, 0.f);
        __syncthreads();

        // fragment-serial edge phase: thread t owns sort-block t's slice of
        // bucket b — cnt consecutive payloads (mean 4 = one 64B line).
        if (t < nSB) {
            unsigned int packed = off_tabT[(size_t)b * nSB + t];   // coalesced
            unsigned int start_g = (unsigned int)t * SEB + (packed & 0xFFFFu);
            unsigned int cnt = packed >> 16;
            for (unsigned int j = 0; j < cnt; ++j)
                process_edge(payload[start_g + j], sC);
        }
        __syncthreads();

        // dense GEMM: [64 x 125] @ [125 x 32]; node = t>>2, cg = t&3 (8 ch/thread)
        const int node = t >> 2;
        const int cg   = t & 3;
        const float* crow = sC + node * SCS;
        float4 accA = make_float4(0.f, 0.f, 0.f, 0.f);
        float4 accB = make_float4(0.f, 0.f, 0.f, 0.f);
        #pragma unroll 4
        for (int k4 = 0; k4 < 31; ++k4) {        // k = 0..123
            float4 r = *(const float4*)&crow[k4 * 4];
            const float* wp = W + (k4 * 4) * F_OUT + cg * 8;
            float4 a0 = *(const float4*)(wp);
            float4 b0 = *(const float4*)(wp + 4);
            float4 a1 = *(const float4*)(wp + F_OUT);
            float4 b1 = *(const float4*)(wp + F_OUT + 4);
            float4 a2 = *(const float4*)(wp + 2 * F_OUT);
            float4 b2 = *(const float4*)(wp + 2 * F_OUT + 4);
            float4 a3 = *(const float4*)(wp + 3 * F_OUT);
            float4 b3 = *(const float4*)(wp + 3 * F_OUT + 4);
            accA.x += r.x * a0.x + r.y * a1.x + r.z * a2.x + r.w * a3.x;
            accA.y += r.x * a0.y + r.y * a1.y + r.z * a2.y + r.w * a3.y;
            accA.z += r.x * a0.z + r.y * a1.z + r.z * a2.z + r.w * a3.z;
            accA.w += r.x * a0.w + r.y * a1.w + r.z * a2.w + r.w * a3.w;
            accB.x += r.x * b0.x + r.y * b1.x + r.z * b2.x + r.w * b3.x;
            accB.y += r.x * b0.y + r.y * b1.y + r.z * b2.y + r.w * b3.y;
            accB.z += r.x * b0.z + r.y * b1.z + r.z * b2.z + r.w * b3.z;
            accB.w += r.x * b0.w + r.y * b1.w + r.z * b2.w + r.w * b3.w;
        }
        {   // k = 124
            float r = crow[124];
            const float* wp = W + 124 * F_OUT + cg * 8;
            accA.x += r * wp[0]; accA.y += r * wp[1];
            accA.z += r * wp[2]; accA.w += r * wp[3];
            accB.x += r * wp[4]; accB.y += r * wp[5];
            accB.z += r * wp[6]; accB.w += r * wp[7];
        }

        // epilogue from registers: mean + root + bias + ELU + voxel atomicMax
        int n = b * NPB + node;
        if (n < Nn) {
            float dg = fmaxf(crow[DEGS], 1.0f);
            float xn = x[n];
            float4 wrA = *(const float4*)(W_root + cg * 8);
            float4 wrB = *(const float4*)(W_root + cg * 8 + 4);
            float4 bsA = *(const float4*)(bias + cg * 8);
            float4 bsB = *(const float4*)(bias + cg * 8 + 4);

            float h0 = accA.x / dg + xn * wrA.x + bsA.x; h0 = h0 > 0.f ? h0 : expm1f(h0);
            float h1 = accA.y / dg + xn * wrA.y + bsA.y; h1 = h1 > 0.f ? h1 : expm1f(h1);
            float h2 = accA.z / dg + xn * wrA.z + bsA.z; h2 = h2 > 0.f ? h2 : expm1f(h2);
            float h3 = accA.w / dg + xn * wrA.w + bsA.w; h3 = h3 > 0.f ? h3 : expm1f(h3);
            float h4 = accB.x / dg + xn * wrB.x + bsB.x; h4 = h4 > 0.f ? h4 : expm1f(h4);
            float h5 = accB.y / dg + xn * wrB.y + bsB.y; h5 = h5 > 0.f ? h5 : expm1f(h5);
            float h6 = accB.z / dg + xn * wrB.z + bsB.z; h6 = h6 > 0.f ? h6 : expm1f(h6);
            float h7 = accB.w / dg + xn * wrB.w + bsB.w; h7 = h7 > 0.f ? h7 : expm1f(h7);

            int vx = min(max((int)floorf(pos[3 * n + 0] * (float)GRID_DIM), 0), GRID_DIM - 1);
            int vy = min(max((int)floorf(pos[3 * n + 1] * (float)GRID_DIM), 0), GRID_DIM - 1);
            int vz = min(max((int)floorf(pos[3 * n + 2] * (float)GRID_DIM), 0), GRID_DIM - 1);
            int vidx = vx + GRID_DIM * vy + GRID_DIM * GRID_DIM * vz;
            unsigned int* pv = pooled + (size_t)vidx * F_OUT + cg * 8;
            atomicMax(pv + 0, enc_f32(h0));
            atomicMax(pv + 1, enc_f32(h1));
            atomicMax(pv + 2, enc_f32(h2));
            atomicMax(pv + 3, enc_f32(h3));
            atomicMax(pv + 4, enc_f32(h4));
            atomicMax(pv + 5, enc_f32(h5));
            atomicMax(pv + 6, enc_f32(h6));
            atomicMax(pv + 7, enc_f32(h7));
        }
        __syncthreads();    // protect sC before next iteration's zeroing
    }
}

// ---------- K3: decode, empty voxels -> 0 ------------------------------------
__global__ __launch_bounds__(256) void finalize_kernel(
    const unsigned int* __restrict__ pooled,
    float* __restrict__ out, int M)
{
    int i = blockIdx.x * blockDim.x + threadIdx.x;
    if (i >= M) return;
    unsigned int u = pooled[i];
    out[i] = (u == 0u) ? 0.0f : dec_f32(u);
}

// ============================ launcher =======================================
extern "C" void kernel_launch(void* const* d_in, const int* in_sizes, int n_in,
                              void* d_out, int out_size, void* d_ws, size_t ws_size,
                              hipStream_t stream) {
    const float* x       = (const float*)d_in[0];
    const int*   ei      = (const int*)  d_in[1];
    const float* pseudo  = (const float*)d_in[2];
    const float* pos     = (const float*)d_in[3];
    const float* W       = (const float*)d_in[4];
    const float* W_root  = (const float*)d_in[5];
    const float* bias    = (const float*)d_in[6];
    float* out = (float*)d_out;

    const int E   = in_sizes[1] / 2;
    const int Nn  = in_sizes[0];                  // F_IN == 1, Nn <= 65536
    const int nSB = (E + SEB - 1) / SEB;          // sort blocks (256 here)
    const int nb  = (Nn + NPB - 1) / NPB;         // owner buckets (1024 here)

    // workspace: [pooled 4MB][off_tab 1MB][off_tabT 1MB][payload 16.8MB]
    const size_t pooled_b = (size_t)NUM_VOX * F_OUT * 4;
    const size_t off_b    = ((size_t)nSB * NBKT * 4 + 255) & ~(size_t)255;
    unsigned int* pooled   = (unsigned int*)d_ws;
    unsigned int* off_tab  = (unsigned int*)((char*)d_ws + pooled_b);
    unsigned int* off_tabT = (unsigned int*)((char*)d_ws + pooled_b + off_b);
    float4*       payload  = (float4*)((char*)d_ws + pooled_b + 2 * off_b);

    hipMemsetAsync(pooled, 0, pooled_b, stream);

    sort_kernel<<<nSB, 512, 0, stream>>>(ei, ei + E, x, pseudo, payload, off_tab, E);
    transpose_kernel<<<dim3((NBKT + 31) / 32, (nSB + 31) / 32), 256, 0, stream>>>(
        off_tab, off_tabT, nSB, NBKT);
    int grid = (nb < OWN_BLOCKS) ? nb : OWN_BLOCKS;
    owner_kernel<<<grid, 256, 0, stream>>>(payload, off_tabT, W, x, W_root, bias,
                                           pos, pooled, Nn, nSB, nb);

    const int M = (out_size < NUM_VOX * F_OUT) ? out_size : NUM_VOX * F_OUT;
    finalize_kernel<<<(M + 255) / 256, 256, 0, stream>>>(pooled, out, M);
}